// Round 17
// baseline (83.298 us; speedup 1.0000x reference)
//
#include <hip/hip_runtime.h>
#include <hip/hip_bf16.h>

typedef __attribute__((ext_vector_type(8))) short short8;
typedef __attribute__((ext_vector_type(4))) float f32x4;
typedef __attribute__((address_space(1))) const unsigned int as1_u32;
typedef __attribute__((address_space(3))) unsigned int as3_u32;

#define BM 128
#define BN 128
#define BK 64
#define NKT 8        // 512 / BK
#define LDSTA 72     // A LDS row: 64 + 8 pad bf16 (16B-aligned rows, verified R1-R10)
#define A_ELE (128 * LDSTA)   // 9216

static __device__ __forceinline__ unsigned short f2bf(float f) {
    union { __hip_bfloat16 h; unsigned short u; } cv;
    cv.h = __float2bfloat16(f);
    return cv.u;
}

__device__ __forceinline__ void gload16(const void* g, void* l) {
    __builtin_amdgcn_global_load_lds((as1_u32*)g, (as3_u32*)l, 16, 0, 0);
}

// Build WbigS (VERIFIED R16): octonion-folded weight, bf16, pre-swizzled.
// Logical Wbig[m][kk] = sum_i C[i,j,k]*W[i,o,f]  (m=o*8+k col, kk=f*8+j K).
// Chunk (nt=m>>7, H=kk>>5) = 128 cols x 32 K, gloaded linearly; within chunk
// col c=m&127, logical granule q=(kk>>3)&3 stored at q^(c&3), elem e=kk&7:
//   idx = (nt*16+H)*4096 + c*32 + (q^(c&3))*8 + e
__global__ __launch_bounds__(256) void build_wbig(const float* __restrict__ W,
                                                  unsigned short* __restrict__ WbigS) {
    __shared__ float C[8][8][8];
    const int t = threadIdx.x;
    for (int i = t; i < 512; i += 256) ((float*)C)[i] = 0.0f;
    __syncthreads();
    if (t == 0) {
        C[0][0][0] = 1.0f;
        for (int i = 1; i < 8; ++i) { C[0][i][i] = 1.0f; C[i][0][i] = 1.0f; C[i][i][0] = -1.0f; }
        const int tr[7][3] = {{1,2,3},{1,4,5},{1,7,6},{2,4,6},{2,5,7},{3,4,7},{3,6,5}};
        for (int q = 0; q < 7; ++q) {
            const int a = tr[q][0], b = tr[q][1], c = tr[q][2];
            const int p[3][3] = {{a,b,c},{b,c,a},{c,a,b}};
            for (int u = 0; u < 3; ++u) {
                C[p[u][0]][p[u][1]][p[u][2]] = 1.0f;
                C[p[u][1]][p[u][0]][p[u][2]] = -1.0f;
            }
        }
    }
    __syncthreads();
    const int e = blockIdx.x * 256 + t;     // 0..262143
    const int m = e >> 9, kk = e & 511;
    const int o = m >> 3, k = m & 7, f = kk >> 3, j = kk & 7;
    float s = 0.0f;
#pragma unroll
    for (int i = 0; i < 8; ++i) s += C[i][j][k] * W[i * 4096 + o * 64 + f];

    const int nt = m >> 7, c = m & 127;
    const int H = kk >> 5, q = (kk >> 3) & 3, e8 = kk & 7;
    WbigS[((nt * 16 + H) * 4096) + c * 32 + ((q ^ (c & 3)) * 8) + e8] = f2bf(s);
}

// Out[65536][512] = X(fp32->bf16) * Wbig^T + bias.
// First config where co-residency AND the staged pipeline fit TOGETHER:
//   8 waves, wave-tile 64x32 -> acc = 32 regs; A reg-staged bf16 (16 regs);
//   B via global_load_lds (0 regs). Total ~100 <= 128 => 4 waves/SIMD
//   (2 blocks/CU, 16 waves/CU). LDS 68 KB. Plain-HIP schedule, ZERO asm:
//   issue A -> issue B -> MFMA (LDS-only) -> cvt+write A -> __syncthreads.
//   Co-resident block covers the drain (m114); no order-pinning (m141).
__global__ __launch_bounds__(512, 4) void oct_gemm(const float* __restrict__ X,
                                                   const unsigned short* __restrict__ WbigS,
                                                   const float* __restrict__ Bias,
                                                   float* __restrict__ Out) {
    __shared__ unsigned short As[2][A_ELE];    // 2 x 18 KB bf16, 72-stride pad
    __shared__ unsigned short Bs[2][2][4096];  // 2 buf x 2 kk-chunks x 8 KB

    // XCD swizzle: the 4 col-tiles of each row-tile on one XCD (share A in L2).
    const int bid = blockIdx.x;          // 0..2047
    const int xcd = bid & 7;
    const int ix  = bid >> 3;            // 0..255
    const int mtile = xcd * 64 + (ix >> 2);
    const int nt    = ix & 3;
    const int rowBase = mtile * BM;
    const int colBase = nt * BN;

    const int t    = threadIdx.x;        // 0..511
    const int lane = t & 63;
    const int w    = t >> 6;             // 0..7
    const int wr   = w >> 2;             // 0..1 (64-row half)
    const int wc   = w & 3;              // 0..3 (32-col quarter)
    const int l15  = lane & 15;
    const int l4   = lane >> 4;          // 0..3

    // A staging: 4 thr/row, 16 consecutive fp32 (64 B) each.
    const int srow = t >> 2;             // 0..127
    const int scol = (t & 3) * 16;       // 0, 16, 32, 48
    const float* Xp = X + (size_t)(rowBase + srow) * 512 + scol;

    // B gload source (R16-verified stream) and frag-read offset.
    const unsigned short* Bsrc = WbigS + nt * (16 * 4096) + t * 8;

    f32x4 va[4];   // depth-1 in-flight A (16 regs)

#define ISSUE_A(KT) do { _Pragma("unroll") \
    for (int l = 0; l < 4; ++l) \
        va[l] = *reinterpret_cast<const f32x4*>(Xp + (KT) * BK + l * 4); \
    } while (0)

#define GLOAD_B(BUF, KT) do { _Pragma("unroll") \
    for (int kk = 0; kk < 2; ++kk) \
        gload16(Bsrc + (2 * (KT) + kk) * 4096, &Bs[BUF][kk][w * 512]); \
    } while (0)

#define WRITE_A(BUF) do { \
    short8 p0, p1; \
    p0[0]=(short)f2bf(va[0][0]); p0[1]=(short)f2bf(va[0][1]); \
    p0[2]=(short)f2bf(va[0][2]); p0[3]=(short)f2bf(va[0][3]); \
    p0[4]=(short)f2bf(va[1][0]); p0[5]=(short)f2bf(va[1][1]); \
    p0[6]=(short)f2bf(va[1][2]); p0[7]=(short)f2bf(va[1][3]); \
    p1[0]=(short)f2bf(va[2][0]); p1[1]=(short)f2bf(va[2][1]); \
    p1[2]=(short)f2bf(va[2][2]); p1[3]=(short)f2bf(va[2][3]); \
    p1[4]=(short)f2bf(va[3][0]); p1[5]=(short)f2bf(va[3][1]); \
    p1[6]=(short)f2bf(va[3][2]); p1[7]=(short)f2bf(va[3][3]); \
    *reinterpret_cast<short8*>(&As[BUF][srow * LDSTA + scol]) = p0; \
    *reinterpret_cast<short8*>(&As[BUF][srow * LDSTA + scol + 8]) = p1; \
    } while (0)

    // Bias folded into accumulator init (D col = lane&15 for all 4 regs).
    f32x4 acc[4][2];
#pragma unroll
    for (int ni = 0; ni < 2; ++ni) {
        const float bv = Bias[colBase + wc * 32 + ni * 16 + l15];
#pragma unroll
        for (int mi = 0; mi < 4; ++mi) acc[mi][ni] = (f32x4){bv, bv, bv, bv};
    }

    // Prologue: tile 0 staged; syncthreads drains (one-time).
    ISSUE_A(0);
    GLOAD_B(0, 0);
    WRITE_A(0);
    __syncthreads();

#pragma unroll
    for (int kt = 0; kt < NKT; ++kt) {
        // Issue next tile's loads first (they land during the MFMA phase).
        if (kt + 1 < NKT) {
            ISSUE_A(kt + 1);
            GLOAD_B((kt + 1) & 1, kt + 1);
        }

        // MFMA phase: LDS-only operands. B un-swizzle: granule l4 ^ (c&3),
        // c&3 = l15&3 (wc*32, ni*16 are multiples of 4).
#pragma unroll
        for (int kk = 0; kk < 2; ++kk) {
            short8 b[2];
#pragma unroll
            for (int ni = 0; ni < 2; ++ni) {
                const int c = wc * 32 + ni * 16 + l15;
                b[ni] = *reinterpret_cast<const short8*>(
                    &Bs[kt & 1][kk][c * 32 + ((l4 ^ (l15 & 3)) << 3)]);
            }
#pragma unroll
            for (int mi = 0; mi < 4; ++mi) {
                const short8 a = *reinterpret_cast<const short8*>(
                    &As[kt & 1][(wr * 64 + mi * 16 + l15) * LDSTA + kk * 32 + l4 * 8]);
#pragma unroll
                for (int ni = 0; ni < 2; ++ni)
                    acc[mi][ni] = __builtin_amdgcn_mfma_f32_16x16x32_bf16(
                        a, b[ni], acc[mi][ni], 0, 0, 0);
            }
        }

        // Stage A(t+1) (compiler-counted wait on va), then full-drain barrier.
        if (kt + 1 < NKT) WRITE_A((kt + 1) & 1);
        __syncthreads();
    }

    // Epilogue: plain fp32 stores (clean 131 MB pattern, verified).
#pragma unroll
    for (int mi = 0; mi < 4; ++mi) {
        const int row0 = rowBase + wr * 64 + mi * 16 + l4 * 4;
#pragma unroll
        for (int ni = 0; ni < 2; ++ni) {
            const int col = colBase + wc * 32 + ni * 16 + l15;
#pragma unroll
            for (int r = 0; r < 4; ++r)
                Out[(size_t)(row0 + r) * 512 + col] = acc[mi][ni][r];
        }
    }
#undef ISSUE_A
#undef GLOAD_B
#undef WRITE_A
}

extern "C" void kernel_launch(void* const* d_in, const int* in_sizes, int n_in,
                              void* d_out, int out_size, void* d_ws, size_t ws_size,
                              hipStream_t stream) {
    const float* x = (const float*)d_in[0];   // [65536][512]
    const float* W = (const float*)d_in[1];   // [8][64][64]
    const float* b = (const float*)d_in[2];   // [512]
    float* out = (float*)d_out;               // [65536][512]
    unsigned short* WbigS = (unsigned short*)d_ws;  // 512 KB pre-swizzled stream

    build_wbig<<<1024, 256, 0, stream>>>(W, WbigS);
    oct_gemm<<<2048, 512, 0, stream>>>(x, WbigS, b, out);
}

// Round 18
// 77.683 us; speedup vs baseline: 1.0723x; 1.0723x over previous
//
#include <hip/hip_runtime.h>
#include <hip/hip_bf16.h>

typedef __attribute__((ext_vector_type(8))) short short8;
typedef __attribute__((ext_vector_type(4))) float f32x4;
typedef __attribute__((address_space(1))) const unsigned int as1_u32;
typedef __attribute__((address_space(3))) unsigned int as3_u32;

#define BM 256
#define BN 256
#define BK 64
#define NKT 8
#define LDSTA 72                  // A row: 64 + 8 pad bf16 (2-way free, verified)
#define A_ELE (256 * LDSTA)       // 18432 per buf
#define B_ELE (2 * 8192)          // per buf: 2 halves x (256 cols x 32 K)
#define LDS_BYTES ((2 * A_ELE + 2 * B_ELE) * 2)   // 139264 B

static __device__ __forceinline__ unsigned short f2bf(float f) {
    union { __hip_bfloat16 h; unsigned short u; } cv;
    cv.h = __float2bfloat16(f);
    return cv.u;
}

__device__ __forceinline__ void gload16(const void* g, void* l) {
    __builtin_amdgcn_global_load_lds((as1_u32*)g, (as3_u32*)l, 16, 0, 0);
}

// Build WbigS (VERIFIED R15): octonion-folded weight, bf16, pre-swizzled.
// Logical Wbig[m][kk] = sum_i C[i,j,k]*W[i,o,f]  (m=o*8+k col, kk=f*8+j K).
// Chunk (nt=m>>8, H=kk>>5) = 256 cols x 32 K = 16 KB, gloaded linearly.
// Within chunk: col c=m&255, granule g=(kk>>3)&3 at g^((c>>1)&3), elem e=kk&7:
//   idx = ((nt*16+H)<<13) + 32*c + 8*(g^((c>>1)&3)) + e
__global__ __launch_bounds__(256) void build_wbig(const float* __restrict__ W,
                                                  unsigned short* __restrict__ WbigS) {
    __shared__ float C[8][8][8];
    const int t = threadIdx.x;
    for (int i = t; i < 512; i += 256) ((float*)C)[i] = 0.0f;
    __syncthreads();
    if (t == 0) {
        C[0][0][0] = 1.0f;
        for (int i = 1; i < 8; ++i) { C[0][i][i] = 1.0f; C[i][0][i] = 1.0f; C[i][i][0] = -1.0f; }
        const int tr[7][3] = {{1,2,3},{1,4,5},{1,7,6},{2,4,6},{2,5,7},{3,4,7},{3,6,5}};
        for (int q = 0; q < 7; ++q) {
            const int a = tr[q][0], b = tr[q][1], c = tr[q][2];
            const int p[3][3] = {{a,b,c},{b,c,a},{c,a,b}};
            for (int u = 0; u < 3; ++u) {
                C[p[u][0]][p[u][1]][p[u][2]] = 1.0f;
                C[p[u][1]][p[u][0]][p[u][2]] = -1.0f;
            }
        }
    }
    __syncthreads();
    const int e = blockIdx.x * 256 + t;     // 0..262143
    const int m = e >> 9, kk = e & 511;
    const int o = m >> 3, k = m & 7, f = kk >> 3, j = kk & 7;
    float s = 0.0f;
#pragma unroll
    for (int i = 0; i < 8; ++i) s += C[i][j][k] * W[i * 4096 + o * 64 + f];

    const int nt = m >> 8, c = m & 255;
    const int H = kk >> 5, g = (kk >> 3) & 3, e8 = kk & 7;
    WbigS[((size_t)(nt * 16 + H) << 13) + 32 * c + 8 * (g ^ ((c >> 1) & 3)) + e8] = f2bf(s);
}

// Out[65536][512] = X(fp32->bf16) * Wbig^T + bias.
// 8-phase (4 phases/K-tile) m201-style schedule on R12's verified operand
// paths. Per phase: {ds_read frags | one stage-slice of tile t+1 | s_barrier |
// setprio + 16 MFMA + setprio | s_barrier}. Stage slices: q0 = 4 B-gloads +
// A-half0 flat loads; q1 = A-half1 loads; q2 = cvt+ds_write half0 (counted
// vmcnt(4), retires B(t+1) in-order); q3 = cvt+ds_write half1 + __syncthreads
// boundary (drain free: all vmem already retired by write deps).
__global__ __launch_bounds__(512, 2) void oct_gemm(const float* __restrict__ X,
                                                   const unsigned short* __restrict__ WbigS,
                                                   const float* __restrict__ Bias,
                                                   float* __restrict__ Out) {
    extern __shared__ unsigned short smem[];
    unsigned short* As[2]  = { smem,             smem + A_ELE };
    unsigned short* Bsm[2] = { smem + 2 * A_ELE, smem + 2 * A_ELE + B_ELE };

    // XCD swizzle: both col-tiles of a row-tile on one XCD (shared A in L2).
    const int bid = blockIdx.x;          // 0..511
    const int xcd = bid & 7;
    const int ix  = bid >> 3;            // 0..63
    const int mtile = xcd * 32 + (ix >> 1);
    const int nt    = ix & 1;
    const int rowBase = mtile * BM;
    const int colBase = nt * BN;

    const int t    = threadIdx.x;        // 0..511
    const int lane = t & 63;
    const int w    = t >> 6;             // 0..7
    const int wr   = w >> 2;             // 0..1  (128-row half)
    const int wc   = w & 3;              // 0..3  (64-col quarter)
    const int l15  = lane & 15;
    const int l4   = lane >> 4;          // 0..3

    // A staging: thread covers row = t>>1, 16 fp32 at (t&1)*16 within each half.
    const int arow = t >> 1;
    const int acol = (t & 1) * 16;
    const float* Xp = X + (size_t)(rowBase + arow) * 512 + acol;

    // B gload source stream (R15-verified chunk layout).
    const unsigned short* Bsrc = WbigS + ((size_t)(nt * 16) << 13) + ((size_t)t << 3);

    f32x4 va0[4], va1[4];                // 2 halves in flight (32 VGPR)

#define ISSUE_A(VA, KT, H) do { _Pragma("unroll") \
    for (int l = 0; l < 4; ++l) \
        VA[l] = *reinterpret_cast<const f32x4*>(Xp + (KT) * BK + (H) * 32 + l * 4); \
    } while (0)

#define WRITE_A(VA, NB, H) do { \
    short8 p0, p1; \
    p0[0]=(short)f2bf(VA[0][0]); p0[1]=(short)f2bf(VA[0][1]); \
    p0[2]=(short)f2bf(VA[0][2]); p0[3]=(short)f2bf(VA[0][3]); \
    p0[4]=(short)f2bf(VA[1][0]); p0[5]=(short)f2bf(VA[1][1]); \
    p0[6]=(short)f2bf(VA[1][2]); p0[7]=(short)f2bf(VA[1][3]); \
    p1[0]=(short)f2bf(VA[2][0]); p1[1]=(short)f2bf(VA[2][1]); \
    p1[2]=(short)f2bf(VA[2][2]); p1[3]=(short)f2bf(VA[2][3]); \
    p1[4]=(short)f2bf(VA[3][0]); p1[5]=(short)f2bf(VA[3][1]); \
    p1[6]=(short)f2bf(VA[3][2]); p1[7]=(short)f2bf(VA[3][3]); \
    *reinterpret_cast<short8*>(&As[NB][arow * LDSTA + (H) * 32 + acol]) = p0; \
    *reinterpret_cast<short8*>(&As[NB][arow * LDSTA + (H) * 32 + acol + 8]) = p1; \
    } while (0)

    // 4 gloads per tile (2 per half): chunk (nt*16 + 2*kt + h), instr i.
#define GLOAD_B(NB, KT) do { _Pragma("unroll") \
    for (int h = 0; h < 2; ++h) \
        _Pragma("unroll") \
        for (int i = 0; i < 2; ++i) \
            gload16(Bsrc + ((size_t)(2 * (KT) + h) << 13) + (i * 512 << 3), \
                    Bsm[NB] + h * 8192 + i * 4096 + w * 512); \
    } while (0)

    // Frag offsets. A: row = wr*128 + mi*16 + l15, + kk*32 + l4*8.
    const int aoff = (wr * 128 + l15) * LDSTA + l4 * 8;
    // B: col c = wc*64 + ni*16 + l15; granule at l4 ^ ((l15>>1)&3); half = kk.
    const int boff = (wc * 64 + l15) * 32 + ((l4 ^ ((l15 >> 1) & 3)) << 3);

    // Bias folded into accumulator init (D col = lane&15 for all 4 regs).
    f32x4 acc[8][4];
#pragma unroll
    for (int ni = 0; ni < 4; ++ni) {
        const float bv = Bias[colBase + wc * 64 + ni * 16 + l15];
#pragma unroll
        for (int mi = 0; mi < 8; ++mi) acc[mi][ni] = (f32x4){bv, bv, bv, bv};
    }

    // Prologue: stage tile 0 (one-time drain).
    ISSUE_A(va0, 0, 0); ISSUE_A(va1, 0, 1);
    GLOAD_B(0, 0);
    WRITE_A(va0, 0, 0); WRITE_A(va1, 0, 1);
    __syncthreads();

#define MFMA_PAIR(Q) do { \
    __builtin_amdgcn_s_setprio(1); \
    _Pragma("unroll") \
    for (int m2 = 0; m2 < 2; ++m2) { \
        const int mi = 2 * (Q) + m2; \
        _Pragma("unroll") \
        for (int kk = 0; kk < 2; ++kk) { \
            const short8 a = *reinterpret_cast<const short8*>( \
                &As[buf][aoff + mi * (16 * LDSTA) + kk * 32]); \
            _Pragma("unroll") \
            for (int ni = 0; ni < 4; ++ni) \
                acc[mi][ni] = __builtin_amdgcn_mfma_f32_16x16x32_bf16( \
                    a, bf[kk][ni], acc[mi][ni], 0, 0, 0); \
        } \
    } \
    __builtin_amdgcn_s_setprio(0); \
    } while (0)

#pragma unroll
    for (int kt = 0; kt < NKT; ++kt) {
        const int buf = kt & 1, nbuf = buf ^ 1;
        const bool pre = (kt + 1 < NKT);

        // B frags for the whole K-tile (8 ds_read_b128, cached in 32 regs).
        short8 bf[2][4];
#pragma unroll
        for (int kk = 0; kk < 2; ++kk)
#pragma unroll
            for (int ni = 0; ni < 4; ++ni)
                bf[kk][ni] = *reinterpret_cast<const short8*>(
                    &Bsm[buf][kk * 8192 + boff + ni * 512]);

        // q0: stage-slice = B gloads + A half0 issue
        if (pre) { GLOAD_B(nbuf, kt + 1); ISSUE_A(va0, kt + 1, 0); }
        __builtin_amdgcn_s_barrier();
        MFMA_PAIR(0);
        __builtin_amdgcn_s_barrier();

        // q1: stage-slice = A half1 issue
        if (pre) ISSUE_A(va1, kt + 1, 1);
        __builtin_amdgcn_s_barrier();
        MFMA_PAIR(1);
        __builtin_amdgcn_s_barrier();

        // q2: stage-slice = write half0 (counted vmcnt(4); retires B in-order)
        if (pre) WRITE_A(va0, nbuf, 0);
        __builtin_amdgcn_s_barrier();
        MFMA_PAIR(2);
        __builtin_amdgcn_s_barrier();

        // q3: stage-slice = write half1; boundary barrier (drain is free)
        if (pre) WRITE_A(va1, nbuf, 1);
        __builtin_amdgcn_s_barrier();
        MFMA_PAIR(3);
        __syncthreads();
    }

    // Epilogue: plain fp32 stores (verified clean 131 MB pattern).
#pragma unroll
    for (int mi = 0; mi < 8; ++mi) {
        const int row0 = rowBase + wr * 128 + mi * 16 + l4 * 4;
#pragma unroll
        for (int ni = 0; ni < 4; ++ni) {
            const int col = colBase + wc * 64 + ni * 16 + l15;
#pragma unroll
            for (int r = 0; r < 4; ++r)
                Out[(size_t)(row0 + r) * 512 + col] = acc[mi][ni][r];
        }
    }
#undef ISSUE_A
#undef WRITE_A
#undef GLOAD_B
#undef MFMA_PAIR
}

extern "C" void kernel_launch(void* const* d_in, const int* in_sizes, int n_in,
                              void* d_out, int out_size, void* d_ws, size_t ws_size,
                              hipStream_t stream) {
    const float* x = (const float*)d_in[0];   // [65536][512]
    const float* W = (const float*)d_in[1];   // [8][64][64]
    const float* b = (const float*)d_in[2];   // [512]
    float* out = (float*)d_out;               // [65536][512]
    unsigned short* WbigS = (unsigned short*)d_ws;  // 512 KB pre-swizzled stream

    static bool attr_done = false;
    if (!attr_done) {
        hipFuncSetAttribute((const void*)oct_gemm,
                            hipFuncAttributeMaxDynamicSharedMemorySize, LDS_BYTES);
        attr_done = true;
    }

    build_wbig<<<1024, 256, 0, stream>>>(W, WbigS);
    oct_gemm<<<512, 512, LDS_BYTES, stream>>>(x, WbigS, b, out);
}